// Round 12
// baseline (210.726 us; speedup 1.0000x reference)
//
#include <hip/hip_runtime.h>

#define SRC_LEN 256
#define TRG_LEN 256
#define BATCH   32
#define HID     512
#define ATT     128
#define CSCALE  2.885390081777927f   // 2*log2(e): exp2(CSCALE*x) == exp(2x)

typedef float  f32x4  __attribute__((ext_vector_type(4)));
typedef float  f32x16 __attribute__((ext_vector_type(16)));
typedef short  bf16x8 __attribute__((ext_vector_type(8)));

// manual RNE fp32->bf16 (inputs are finite normals; NaN path not needed)
__device__ inline unsigned short bfr(float x) {
    unsigned u = __builtin_bit_cast(unsigned, x);
    return (unsigned short)((u + 0x7fffu + ((u >> 16) & 1u)) >> 16);
}
__device__ inline unsigned pk2(float a, float b) {
    return (unsigned)bfr(a) | ((unsigned)bfr(b) << 16);
}

// ---------------------------------------------------------------------------
// MFMA projection v5 core (R9-measured-best, ~22 us): 256 blocks x 512
// threads, 64-row x 128-a tile, coalesced dbuf LDS staging. Settled lessons:
// R5 divergent W loads +14.5 us; R10 16-row tiles +6.6 us (staging:compute).
// R11 change (dec epilogue only): write score-ready records
// decR[b][t>>2][a>>2][ d(t&3,a&3) x16 | v*d x16 ] so score's wave-uniform
// operands arrive as two s_load_dwordx16 (scalar pipe) instead of 5
// ds_read_b128 broadcasts per g — LDS was score's binding pipe (~25.6 us).
// ---------------------------------------------------------------------------
__global__ __launch_bounds__(512) void proj_mfma(
    const float* __restrict__ dec_out, const float* __restrict__ enc_outs,
    const float* __restrict__ W_s, const float* __restrict__ W_t,
    const float* __restrict__ b_t, const float* __restrict__ v_a,
    float* __restrict__ encE, float* __restrict__ decR)
{
    __shared__ __align__(16) char smem[49152];
    char* aLb = smem;            // [2][64 rows][128 B] = 16 KB
    char* bLb = smem + 16384;    // [2][128 rows][128 B] = 32 KB

    const int tid   = threadIdx.x;
    const int blk   = blockIdx.x;
    const bool isDec = blk >= 128;
    const int bb    = blk & 31;
    const int r0    = ((isDec ? blk - 128 : blk) >> 5) * 64;  // s0 or t0
    const float* __restrict__ in = isDec ? dec_out : enc_outs;
    const float* __restrict__ W  = isDec ? W_t : W_s;

    const int lane   = tid & 63;
    const int w      = tid >> 6;        // 0..7
    const int woff_m = (w & 3) * 16;
    const int woff_n = (w >> 2) * 64;
    const int q      = lane >> 4;
    const int l15    = lane & 15;
    const int l7     = lane & 7;

    const int srow = tid >> 4;
    const int skc  = tid & 15;
    const int sg   = skc >> 1, shalf = skc & 1;   // 16B LDS group, 8B half
    const float* aGp = in + ((size_t)(r0 + srow) * BATCH + bb) * HID + skc * 4;
    const float* wGp = W + (size_t)srow * HID + skc * 4;

    float4 aR[2];   // A rows srow, srow+32
    float4 wR[4];   // W rows srow + it*32

    f32x4 acc[4];
    #pragma unroll
    for (int ni = 0; ni < 4; ++ni) acc[ni] = (f32x4)0.0f;

    #define LOADG(c)                                                          \
        {                                                                     \
            _Pragma("unroll")                                                 \
            for (int it = 0; it < 2; ++it)                                    \
                aR[it] = *(const float4*)(aGp + (size_t)it * 32 * BATCH * HID \
                                          + (c) * 64);                        \
            _Pragma("unroll")                                                 \
            for (int it = 0; it < 4; ++it)                                    \
                wR[it] = *(const float4*)(wGp + (size_t)it * 32 * HID         \
                                          + (c) * 64);                        \
        }

    #define STORES(buf)                                                      \
        {                                                                    \
            char* ab = aLb + (buf) * 8192;                                   \
            _Pragma("unroll")                                                \
            for (int it = 0; it < 2; ++it) {                                 \
                const int i = srow + it * 32;                                \
                uint2 u;                                                     \
                u.x = pk2(aR[it].x, aR[it].y);                               \
                u.y = pk2(aR[it].z, aR[it].w);                               \
                *(uint2*)(ab + i * 128 + ((sg ^ (i & 7)) << 4)               \
                          + shalf * 8) = u;                                  \
            }                                                                \
            char* bp = bLb + (buf) * 16384;                                  \
            _Pragma("unroll")                                                \
            for (int it = 0; it < 4; ++it) {                                 \
                const int rw = srow + it * 32;                               \
                uint2 u;                                                     \
                u.x = pk2(wR[it].x, wR[it].y);                               \
                u.y = pk2(wR[it].z, wR[it].w);                               \
                *(uint2*)(bp + rw * 128 + ((sg ^ (rw & 7)) << 4)             \
                          + shalf * 8) = u;                                  \
            }                                                                \
        }

    LOADG(0);
    STORES(0);
    __syncthreads();

    for (int c = 0; c < 8; ++c) {
        if (c < 7) LOADG(c + 1);
        const char* ab = aLb + (c & 1) * 8192;
        const char* bp = bLb + (c & 1) * 16384;
        #pragma unroll
        for (int s = 0; s < 2; ++s) {
            const int sw = ((s * 4 + q) ^ l7) * 16;
            bf16x8 af = *(const bf16x8*)(ab + (woff_m + l15) * 128 + sw);
            bf16x8 bfv[4];
            #pragma unroll
            for (int ni = 0; ni < 4; ++ni)
                bfv[ni] = *(const bf16x8*)(bp + (woff_n + ni * 16 + l15) * 128 + sw);
            #pragma unroll
            for (int ni = 0; ni < 4; ++ni)
                acc[ni] = __builtin_amdgcn_mfma_f32_16x16x32_bf16(
                    af, bfv[ni], acc[ni], 0, 0, 0);
        }
        if (c < 7) STORES((c + 1) & 1);
        __syncthreads();
    }

    if (!isDec) {
        // E' = exp(-2*enc_att) -> LDS transpose (stride 132) ->
        // [b][a>>2][s][4] store: one coalesced float4 per lane for score.
        float* T = (float*)smem;
        #pragma unroll
        for (int ni = 0; ni < 4; ++ni)
            #pragma unroll
            for (int r = 0; r < 4; ++r) {
                const int ml = woff_m + q * 4 + r;
                const int nl = woff_n + ni * 16 + l15;
                T[ml * 132 + nl] = __builtin_amdgcn_exp2f(-CSCALE * acc[ni][r]);
            }
        __syncthreads();
        {
            const int m  = tid & 63;     // s-local
            const int g0 = tid >> 6;     // 0..7
            #pragma unroll
            for (int p = 0; p < 4; ++p) {
                const int gq = g0 + p * 8;          // a-quad 0..31
                float4 v = *(const float4*)(T + m * 132 + gq * 4);
                *(float4*)(encE + (((size_t)bb * 32 + gq) * SRC_LEN + r0 + m) * 4) = v;
            }
        }
    } else {
        // D = exp(+2*(dec_att + b_t)); write record layout:
        // decR[((b*64 + t>>2)*32 + a>>2)*32 + (t&3)*4 + (a&3)]       = D
        // decR[ ...same...                 + 16 ]                    = v_a*D
        float bt[4], vA[4];
        #pragma unroll
        for (int ni = 0; ni < 4; ++ni) {
            bt[ni] = b_t[woff_n + ni * 16 + l15];
            vA[ni] = v_a[woff_n + ni * 16 + l15];
        }
        const int tqB = (r0 + woff_m) >> 2;           // + q below
        const int i   = l15 & 3;
        #pragma unroll
        for (int ni = 0; ni < 4; ++ni) {
            const int g = ((woff_n + ni * 16) >> 2) + (l15 >> 2);
            #pragma unroll
            for (int r = 0; r < 4; ++r) {
                const float Dv = __builtin_amdgcn_exp2f(CSCALE * (acc[ni][r] + bt[ni]));
                float* p = decR + (((size_t)bb * 64 + (tqB + q)) * 32 + g) * 32 + r * 4 + i;
                p[0]  = Dv;
                p[16] = vA[ni] * Dv;
            }
        }
    }
    #undef LOADG
    #undef STORES
}

// ---------------------------------------------------------------------------
// Score v8: ZERO LDS. Identity: v*tanh = 2*v*D/(D+E') - v, so the quad
// numerators n_i = v_i*D_i are wave-uniform and precomputed by proj.
// Per g: two s_load_dwordx16 (d16|n16 record, scalar pipe, K$-hot 4 KB/block)
// + one per-lane global dwordx4 for E. Software-pipelined one record ahead;
// s_waitcnt lgkmcnt(0) placed BEFORE issuing the next record so only the
// (one-body-old) current record is drained. R11 diagnosis: the 5 broadcast
// ds_read_b128/g were the binding pipe (~25.6 us/CU); SMEM replaces them.
//   acc += [ (n0x1+n1x0)a23 + (n2x3+n3x2)a01 ] / (a01*a23),  x_i = E_i+d_i
//   out = 2*acc - sumV
// ---------------------------------------------------------------------------
__global__ __launch_bounds__(256) void score_kernel(
    const float* __restrict__ encE, const float* __restrict__ decR,
    const float* __restrict__ v_a, float* __restrict__ out)
{
    const int tid = threadIdx.x;
    const int tq  = blockIdx.x;          // t-quad
    const int b   = blockIdx.y;

    // sumV: uniform loads + adds (one-time, trivial)
    float sv = 0.f;
    #pragma unroll
    for (int g = 0; g < 32; ++g) {
        const float4 v4 = *(const float4*)(v_a + g * 4);
        sv += (v4.x + v4.y) + (v4.z + v4.w);
    }

    const float* __restrict__ ep = encE + ((size_t)b * 32 * SRC_LEN + tid) * 4;
    const float* rp = decR + ((size_t)b * 64 + tq) * 32 * 32;   // g=0 record

    f32x16 d0, n0, d1, n1;
    asm volatile("s_load_dwordx16 %0, %2, 0x0\n\t"
                 "s_load_dwordx16 %1, %2, 0x40"
                 : "=s"(d0), "=s"(n0) : "s"(rp));

    float acc0 = 0.f, acc1 = 0.f, acc2 = 0.f, acc3 = 0.f;

    #pragma unroll
    for (int g = 0; g < 32; ++g) {
        // drain current record (issued one loop body ago)
        if (g & 1) { asm volatile("s_waitcnt lgkmcnt(0)" : "+s"(d1), "+s"(n1)); }
        else       { asm volatile("s_waitcnt lgkmcnt(0)" : "+s"(d0), "+s"(n0)); }
        // issue next record; its latency hides under this body's VALU
        if (g < 31) {
            const float* np = rp + (size_t)(g + 1) * 32;
            if (g & 1)
                asm volatile("s_load_dwordx16 %0, %2, 0x0\n\t"
                             "s_load_dwordx16 %1, %2, 0x40"
                             : "=s"(d0), "=s"(n0) : "s"(np));
            else
                asm volatile("s_load_dwordx16 %0, %2, 0x0\n\t"
                             "s_load_dwordx16 %1, %2, 0x40"
                             : "=s"(d1), "=s"(n1) : "s"(np));
        }
        const f32x16 dd = (g & 1) ? d1 : d0;
        const f32x16 nn = (g & 1) ? n1 : n0;
        const float4 E  = *(const float4*)(ep + (size_t)g * SRC_LEN * 4);

        #define TSTEP(ACC, T)                                                 \
        {                                                                     \
            const float x0 = E.x + dd[(T) * 4 + 0];                           \
            const float x1 = E.y + dd[(T) * 4 + 1];                           \
            const float x2 = E.z + dd[(T) * 4 + 2];                           \
            const float x3 = E.w + dd[(T) * 4 + 3];                           \
            const float a01 = x0 * x1, a23 = x2 * x3;                         \
            const float den = a01 * a23;                                      \
            const float m01 = fmaf(nn[(T) * 4 + 0], x1,                       \
                                   nn[(T) * 4 + 1] * x0);                     \
            const float m23 = fmaf(nn[(T) * 4 + 2], x3,                       \
                                   nn[(T) * 4 + 3] * x2);                     \
            const float num = fmaf(m01, a23, m23 * a01);                      \
            ACC = fmaf(num, __builtin_amdgcn_rcpf(den), ACC);                 \
        }
        TSTEP(acc0, 0)
        TSTEP(acc1, 1)
        TSTEP(acc2, 2)
        TSTEP(acc3, 3)
        #undef TSTEP
    }

    const int t0 = tq * 4;
    out[((size_t)(t0 + 0) * BATCH + b) * SRC_LEN + tid] = 2.0f * acc0 - sv;
    out[((size_t)(t0 + 1) * BATCH + b) * SRC_LEN + tid] = 2.0f * acc1 - sv;
    out[((size_t)(t0 + 2) * BATCH + b) * SRC_LEN + tid] = 2.0f * acc2 - sv;
    out[((size_t)(t0 + 3) * BATCH + b) * SRC_LEN + tid] = 2.0f * acc3 - sv;
}

extern "C" void kernel_launch(void* const* d_in, const int* in_sizes, int n_in,
                              void* d_out, int out_size, void* d_ws, size_t ws_size,
                              hipStream_t stream) {
    const float* dec_out  = (const float*)d_in[0];
    const float* enc_outs = (const float*)d_in[1];
    const float* W_s      = (const float*)d_in[2];
    const float* W_t      = (const float*)d_in[3];
    const float* b_t      = (const float*)d_in[4];
    const float* v_a      = (const float*)d_in[5];
    float* out = (float*)d_out;

    float* encE = (float*)d_ws;                              // 4 MB : exp(-2*enc_att), [b][a>>2][s][4]
    float* decR = encE + (size_t)BATCH * ATT * SRC_LEN;      // 8 MB : records [b][t>>2][a>>2][d16|n16]

    proj_mfma<<<256, 512, 0, stream>>>(dec_out, enc_outs, W_s, W_t, b_t, v_a, encE, decR);

    dim3 g3(TRG_LEN / 4, BATCH);
    score_kernel<<<g3, 256, 0, stream>>>(encE, decR, v_a, out);
}